// Round 3
// baseline (1615.835 us; speedup 1.0000x reference)
//
#include <hip/hip_runtime.h>
#include <hip/hip_bf16.h>

#define HID 128
#define SEQ 2048
#define BATCH 64
#define NOUT 512

typedef __attribute__((ext_vector_type(8))) short bf16x8;
typedef __attribute__((ext_vector_type(4))) float f32x4;

__device__ __forceinline__ short f2bf(float f) {
    unsigned u = __float_as_uint(f);
    unsigned r = u + 0x7fffu + ((u >> 16) & 1u);   // RNE
    return (short)(r >> 16);
}

__device__ __forceinline__ float fast_sigmoid(float x) {
    return 1.0f / (1.0f + __expf(-x));
}

__device__ __forceinline__ float fast_tanh(float x) {
    return 1.0f - 2.0f / (__expf(2.0f * x) + 1.0f);
}

// Forced-VGPR FMA: round-2 counters showed VGPR_Count=64 with 96 live
// weight floats -> compiler parked weights in AGPRs and paid move/issue
// overhead on every MAC (active-CU VALUBusy ~88%, ~2x the hand-counted
// instruction floor). The "v" constraints pin operands to arch VGPRs.
__device__ __forceinline__ void vfmac(float& acc, float a, float b) {
    asm("v_fmac_f32 %0, %1, %2" : "+v"(acc) : "v"(a), "v"(b));
}

// lane^1 within quad: quad_perm [1,0,3,2] = 0xB1
__device__ __forceinline__ float dpp_xor1(float x) {
    int y = __builtin_amdgcn_update_dpp(0, __builtin_bit_cast(int, x),
                                        0xB1, 0xF, 0xF, true);
    return __builtin_bit_cast(float, y);
}
// lane^2 within quad: quad_perm [2,3,0,1] = 0x4E
__device__ __forceinline__ float dpp_xor2(float x) {
    int y = __builtin_amdgcn_update_dpp(0, __builtin_bit_cast(int, x),
                                        0x4E, 0xF, 0xF, true);
    return __builtin_bit_cast(float, y);
}

// ---------------------------------------------------------------------------
// GRU recurrence. One block per batch element (64 blocks -> 64 CUs).
// 512 threads = 8 waves = 2 waves/SIMD. Thread (h = tid>>2, s = tid&3)
// owns gate rows {h,128+h,256+h} over a 32-col slice: 96 f32 weights,
// pinned to arch VGPRs via inline-asm v_fmac (see vfmac note).
//   - h in 4 padded LDS slices (stride 40 words) -> zero bank conflicts
//     (verified: SQ_LDS_BANK_CONFLICT 3.35e7 -> 0 in round 2).
//   - cross-slice reduce = 2 DPP quad-perm adds (VALU-only).
//   - h_old register-carried; one raw s_barrier/step, LDS-only drain.
// ---------------------------------------------------------------------------
__global__ __launch_bounds__(512) void gru_seq(
    const float* __restrict__ latent,   // [BATCH][HID]
    const float* __restrict__ W_hh,     // [3*HID][HID]
    const float* __restrict__ b_ih,     // [3*HID]
    const float* __restrict__ b_hh,     // [3*HID]
    __hip_bfloat16* __restrict__ hs)    // [BATCH][SEQ][HID]  (bf16)
{
    const int b   = blockIdx.x;
    const int tid = threadIdx.x;        // 0..511
    const int h   = tid >> 2;           // 0..127
    const int s   = tid & 3;            // 32-col slice index

    // 4 slices of 32 floats, slice base stride 40 words (160B, 16B-aligned;
    // bank offsets 0/8/16/24 -> disjoint bank groups for the 4 slices)
    __shared__ __align__(16) float hbuf[2][152];

    // 96 weights per thread -> arch VGPRs (asm-pinned at use sites)
    float wr[32], wz[32], wn[32];
    {
        const float4* pr = (const float4*)(W_hh + (size_t)h * HID + s * 32);
        const float4* pz = (const float4*)(W_hh + (size_t)(h + HID) * HID + s * 32);
        const float4* pn = (const float4*)(W_hh + (size_t)(h + 2 * HID) * HID + s * 32);
        #pragma unroll
        for (int k4 = 0; k4 < 8; k4++) {
            float4 v;
            v = pr[k4];
            wr[4 * k4 + 0] = v.x; wr[4 * k4 + 1] = v.y;
            wr[4 * k4 + 2] = v.z; wr[4 * k4 + 3] = v.w;
            v = pz[k4];
            wz[4 * k4 + 0] = v.x; wz[4 * k4 + 1] = v.y;
            wz[4 * k4 + 2] = v.z; wz[4 * k4 + 3] = v.w;
            v = pn[k4];
            wn[4 * k4 + 0] = v.x; wn[4 * k4 + 1] = v.y;
            wn[4 * k4 + 2] = v.z; wn[4 * k4 + 3] = v.w;
        }
    }
    // folded biases: r = sig(cr + ar), z = sig(cz + az),
    // n = tanh(bin + r*(an + bhn))
    const float cr  = b_ih[h] + b_hh[h];
    const float cz  = b_ih[HID + h] + b_hh[HID + h];
    const float bin = b_ih[2 * HID + h];
    const float bhn = b_hh[2 * HID + h];

    float hold = latent[b * HID + h];                  // register-carried h
    const int hword = (h >> 5) * 40 + (h & 31);        // padded slice word
    if (s == 0) hbuf[0][hword] = hold;
    __syncthreads();

    __hip_bfloat16* out_p = hs + (size_t)b * SEQ * HID + h;

    int p = 0;
    for (int t = 0; t < SEQ; t++) {
        float ar = 0.f, az = 0.f, an = 0.f;
        const float4* h4 = (const float4*)&hbuf[p][s * 40];
        #pragma unroll
        for (int k4 = 0; k4 < 8; k4++) {
            float4 hv = h4[k4];                        // conflict-free by pad
            vfmac(ar, hv.x, wr[4 * k4 + 0]);
            vfmac(ar, hv.y, wr[4 * k4 + 1]);
            vfmac(ar, hv.z, wr[4 * k4 + 2]);
            vfmac(ar, hv.w, wr[4 * k4 + 3]);
            vfmac(az, hv.x, wz[4 * k4 + 0]);
            vfmac(az, hv.y, wz[4 * k4 + 1]);
            vfmac(az, hv.z, wz[4 * k4 + 2]);
            vfmac(az, hv.w, wz[4 * k4 + 3]);
            vfmac(an, hv.x, wn[4 * k4 + 0]);
            vfmac(an, hv.y, wn[4 * k4 + 1]);
            vfmac(an, hv.z, wn[4 * k4 + 2]);
            vfmac(an, hv.w, wn[4 * k4 + 3]);
        }
        // 4-slice reduce entirely on the VALU (quad-local DPP butterflies)
        ar += dpp_xor1(ar);  az += dpp_xor1(az);  an += dpp_xor1(an);
        ar += dpp_xor2(ar);  az += dpp_xor2(az);  an += dpp_xor2(an);

        float r  = fast_sigmoid(cr + ar);
        float z  = fast_sigmoid(cz + az);
        float n  = fast_tanh(bin + r * (an + bhn));
        float hn = (1.0f - z) * n + z * hold;
        hold = hn;

        if (s == 0) {
            hbuf[p ^ 1][hword] = hn;                   // write buffer, no race
        } else if (s == 1) {
            out_p[t * HID] =
                __builtin_bit_cast(__hip_bfloat16, (unsigned short)f2bf(hn));
        }

        // LDS-only drain + raw barrier: global history stores stay in flight
        asm volatile("s_waitcnt lgkmcnt(0)" ::: "memory");
        __builtin_amdgcn_s_barrier();
        asm volatile("" ::: "memory");
        p ^= 1;
    }
}

// ---------------------------------------------------------------------------
// Repack fc_W (f32 [512][128]) into bf16 MFMA fragment order:
//   wfrag[((ct*4 + q)*64 + lane)*8 + j] = bf16(fc_W[ct*16 + (lane&15)]
//                                                  [q*32 + (lane>>4)*8 + j])
// ---------------------------------------------------------------------------
__global__ void wprep(const float* __restrict__ fc_W,
                      __hip_bfloat16* __restrict__ wfrag)
{
    int t = blockIdx.x * 256 + threadIdx.x;      // 0..65535
    int j    = t & 7;
    int lane = (t >> 3) & 63;
    int q    = (t >> 9) & 3;
    int ct   = t >> 11;
    int n = ct * 16 + (lane & 15);
    int k = q * 32 + (lane >> 4) * 8 + j;
    unsigned short v = (unsigned short)f2bf(fc_W[n * HID + k]);
    wfrag[t] = __builtin_bit_cast(__hip_bfloat16, v);
}

// ---------------------------------------------------------------------------
// Projection: out[row][o] = sum_k hs[row][k] * fc_W[o][k] + fc_b[o]
// M = 131072, N = 512, K = 128. bf16 MFMA 16x16x32, operand-swapped
// (weights as A) so each lane's acc regs are consecutive output columns.
// NEW: ct-PAIRS per iteration -> per row each lane-pair covers 32
// consecutive columns = a FULL 128B cache line per row. Rounds 1-2 wrote
// 64B per row at 2KB stride (partial-line RMW, ~1.2 TB/s effective);
// proj never moved (~250us vs 48us write roofline). Full-line writes fix it.
// ---------------------------------------------------------------------------
__global__ __launch_bounds__(256) void proj_mfma(
    const __hip_bfloat16* __restrict__ hsb,    // [M][128] bf16
    const __hip_bfloat16* __restrict__ wfrag,  // fragment-ordered [32][4][64][8]
    const float* __restrict__ fc_b,            // [512]
    float* __restrict__ out)                   // [M][512] f32
{
    const int lane = threadIdx.x & 63;
    const int wave = threadIdx.x >> 6;
    const int m    = lane & 15;
    const int quad = lane >> 4;

    const long r0 = ((long)blockIdx.x * 4 + wave) * 32;

    bf16x8 bfrag[2][4];                         // hs rows as the B operand
    #pragma unroll
    for (int rt = 0; rt < 2; rt++) {
        #pragma unroll
        for (int q = 0; q < 4; q++) {
            const __hip_bfloat16* p =
                hsb + (r0 + rt * 16 + m) * HID + q * 32 + quad * 8;
            bfrag[rt][q] = *(const bf16x8*)p;   // 16B aligned
        }
    }

    for (int ct2 = 0; ct2 < 16; ct2++) {
        const int ct0 = 2 * ct2;
        f32x4 acc00 = {0.f, 0.f, 0.f, 0.f};    // [row tile][ct of pair]
        f32x4 acc01 = {0.f, 0.f, 0.f, 0.f};
        f32x4 acc10 = {0.f, 0.f, 0.f, 0.f};
        f32x4 acc11 = {0.f, 0.f, 0.f, 0.f};
        #pragma unroll
        for (int q = 0; q < 4; q++) {
            bf16x8 aw0 = *(const bf16x8*)(wfrag + (((ct0)     * 4 + q) * 64 + lane) * 8);
            bf16x8 aw1 = *(const bf16x8*)(wfrag + (((ct0 + 1) * 4 + q) * 64 + lane) * 8);
            acc00 = __builtin_amdgcn_mfma_f32_16x16x32_bf16(aw0, bfrag[0][q], acc00, 0, 0, 0);
            acc01 = __builtin_amdgcn_mfma_f32_16x16x32_bf16(aw1, bfrag[0][q], acc01, 0, 0, 0);
            acc10 = __builtin_amdgcn_mfma_f32_16x16x32_bf16(aw0, bfrag[1][q], acc10, 0, 0, 0);
            acc11 = __builtin_amdgcn_mfma_f32_16x16x32_bf16(aw1, bfrag[1][q], acc11, 0, 0, 0);
        }
        const int n0 = ct0 * 16 + quad * 4;     // cols n0..n0+3 and n0+16..+19
        const float4 bias0 = *(const float4*)&fc_b[n0];
        const float4 bias1 = *(const float4*)&fc_b[n0 + 16];
        float4 o;
        float* row0 = &out[(r0 + m) * NOUT];
        float* row1 = &out[(r0 + 16 + m) * NOUT];
        o.x = acc00[0] + bias0.x; o.y = acc00[1] + bias0.y;
        o.z = acc00[2] + bias0.z; o.w = acc00[3] + bias0.w;
        *(float4*)&row0[n0] = o;
        o.x = acc01[0] + bias1.x; o.y = acc01[1] + bias1.y;
        o.z = acc01[2] + bias1.z; o.w = acc01[3] + bias1.w;
        *(float4*)&row0[n0 + 16] = o;
        o.x = acc10[0] + bias0.x; o.y = acc10[1] + bias0.y;
        o.z = acc10[2] + bias0.z; o.w = acc10[3] + bias0.w;
        *(float4*)&row1[n0] = o;
        o.x = acc11[0] + bias1.x; o.y = acc11[1] + bias1.y;
        o.z = acc11[2] + bias1.z; o.w = acc11[3] + bias1.w;
        *(float4*)&row1[n0 + 16] = o;
    }
}

extern "C" void kernel_launch(void* const* d_in, const int* in_sizes, int n_in,
                              void* d_out, int out_size, void* d_ws, size_t ws_size,
                              hipStream_t stream) {
    const float* latent = (const float*)d_in[0];   // (64,128)
    const float* W_hh   = (const float*)d_in[1];   // (384,128)
    const float* b_ih   = (const float*)d_in[2];   // (384,)
    const float* b_hh   = (const float*)d_in[3];   // (384,)
    const float* fc_W   = (const float*)d_in[4];   // (512,128)
    const float* fc_b   = (const float*)d_in[5];   // (512,)
    float* out = (float*)d_out;                    // (64,2048,512)

    __hip_bfloat16* hsb   = (__hip_bfloat16*)d_ws;                   // 33.5 MB
    __hip_bfloat16* wfrag = (__hip_bfloat16*)((char*)d_ws + (size_t)BATCH * SEQ * HID * 2);

    wprep<<<256, 256, 0, stream>>>(fc_W, wfrag);
    gru_seq<<<BATCH, 512, 0, stream>>>(latent, W_hh, b_ih, b_hh, hsb);

    const int M = BATCH * SEQ;                     // 131072
    proj_mfma<<<M / 128, 256, 0, stream>>>(hsb, wfrag, fc_b, out);
}